// Round 7
// baseline (294.660 us; speedup 1.0000x reference)
//
#include <hip/hip_runtime.h>

#define N_NODES 20000
#define DEG 16
#define GRAPHS 16
#define NPG 1250

typedef __bf16 bf16x8 __attribute__((ext_vector_type(8)));
typedef float f32x4 __attribute__((ext_vector_type(4)));
#define MFMA16(a, b, c) __builtin_amdgcn_mfma_f32_16x16x32_bf16(a, b, c, 0, 0, 0)

// ---- workspace layout (bf16 element offsets) ----
#define OFF_X1    0            // x1 [20000][128] bf16
#define OFF_P1    2560000      // c1W1 packed: MT=8  KT=1 -> 4096
#define OFF_P2    2564096      // c1W2 packed: MT=8  KT=4 -> 16384
#define OFF_P3    2580480      // c2W1 packed: MT=16 KT=5 -> 40960
#define OFF_P4    2621440      // c2W2 packed: MT=16 KT=8 -> 65536
#define OFF_POOL_BYTES 5373952 // pooled u32[16*256]

// Frag layout (A-role == B-role for mfma_f32_16x16x32_bf16):
//   frag[((t*KT+kt)*64+lane)*8 + j] = X[k = kt*32 + (lane>>4)*8 + j][idx = lane&15]
__global__ __launch_bounds__(256) void pack_weights(
    const float* __restrict__ c1W1, const float* __restrict__ c1W2,
    const float* __restrict__ c2W1, const float* __restrict__ c2W2,
    __bf16* __restrict__ p1, __bf16* __restrict__ p2,
    __bf16* __restrict__ p3, __bf16* __restrict__ p4,
    unsigned int* __restrict__ pooled)
{
    int t = blockIdx.x * 256 + threadIdx.x;
    if (t < GRAPHS * 256) pooled[t] = 0u;   // flipped(-inf) == 0
    if (t >= 15872) return;
    const float* W; __bf16* out; int M, Kreal, KT, grp;
    if      (t <  512)  { W = c1W1; out = p1; M = 128; Kreal =   6; KT = 1; grp = t; }
    else if (t < 2560)  { W = c1W2; out = p2; M = 128; Kreal = 128; KT = 4; grp = t - 512; }
    else if (t < 7680)  { W = c2W1; out = p3; M = 256; Kreal = 131; KT = 5; grp = t - 2560; }
    else                { W = c2W2; out = p4; M = 256; Kreal = 256; KT = 8; grp = t - 7680; }
    int lane = grp & 63, rest = grp >> 6;
    int kt = rest % KT, mt = rest / KT;
    int m = mt * 16 + (lane & 15);
    int kbase = kt * 32 + ((lane >> 4) << 3);
    bf16x8 v;
    #pragma unroll
    for (int j = 0; j < 8; j++) {
        int k = kbase + j;
        v[j] = (k < Kreal) ? (__bf16)W[k * M + m] : (__bf16)0.f;
    }
    *(bf16x8*)&out[grp * 8] = v;
}

// =================== conv1 ===================
// 1250 blocks x 16 nodes. msg B-frags gathered straight to registers (quad-0
// lanes carry k=0..5, rest zero). ONE barrier per block (per 16 nodes).
#define NB1 16
__global__ __launch_bounds__(256, 2) void conv1_kernel(
    const float* __restrict__ pos, const int* __restrict__ esrc,
    const __bf16* __restrict__ W1p, const float* __restrict__ b1,
    const __bf16* __restrict__ W2p, const float* __restrict__ b2,
    __bf16* __restrict__ x1)
{
    __shared__ __attribute__((aligned(16))) __bf16 hidF[NB1 * 4 * 64 * 8];  // 64 KB
    const int tid = threadIdx.x, lane = tid & 63, wave = tid >> 6;
    const int quad = lane >> 4, col = lane & 15;
    const int node0 = blockIdx.x * NB1;

    bf16x8 A1[2], B2w[2][4];
    f32x4 bias1[2];
    float b2v[2];
    #pragma unroll
    for (int i = 0; i < 2; i++) {
        int mtg = wave * 2 + i;
        A1[i] = *(const bf16x8*)&W1p[(mtg * 64 + lane) * 8];
        bias1[i] = *(const f32x4*)&b1[mtg * 16 + quad * 4];
        #pragma unroll
        for (int kt = 0; kt < 4; kt++)
            B2w[i][kt] = *(const bf16x8*)&W2p[((mtg * 4 + kt) * 64 + lane) * 8];
        b2v[i] = b2[mtg * 16 + col];
    }

    // ---- phase 1: gather msg to regs, MFMA, write hid frags ----
    #pragma unroll
    for (int nl = 0; nl < NB1; nl++) {
        bf16x8 B;
        #pragma unroll
        for (int j = 0; j < 8; j++) B[j] = (__bf16)0.f;
        if (quad == 0) {
            int d = node0 + nl;
            int s = esrc[d * 16 + col];
            float sx = pos[3*s], sy = pos[3*s+1], sz = pos[3*s+2];
            B[0] = (__bf16)sx; B[1] = (__bf16)sy; B[2] = (__bf16)sz;
            B[3] = (__bf16)(sx - pos[3*d]);
            B[4] = (__bf16)(sy - pos[3*d+1]);
            B[5] = (__bf16)(sz - pos[3*d+2]);
        }
        #pragma unroll
        for (int i = 0; i < 2; i++) {
            int mtg = wave * 2 + i;
            f32x4 acc = bias1[i];
            acc = MFMA16(A1[i], B, acc);
            union { __bf16 h[4]; uint2 u; } pk;
            #pragma unroll
            for (int r = 0; r < 4; r++) pk.h[r] = (__bf16)fmaxf(acc[r], 0.f);
            int kt2 = mtg >> 1;
            int lane2 = ((mtg * 2 + (quad >> 1)) & 3) * 16 + col;
            int j0 = (quad & 1) * 4;
            *(uint2*)&hidF[((nl * 4 + kt2) * 64 + lane2) * 8 + j0] = pk.u;
        }
    }
    __syncthreads();

    // ---- phase 2: D[edge][ch], edge-max, write x1 ----
    #pragma unroll
    for (int nl = 0; nl < NB1; nl++) {
        bf16x8 hA[4];
        #pragma unroll
        for (int kt = 0; kt < 4; kt++)
            hA[kt] = *(const bf16x8*)&hidF[((nl * 4 + kt) * 64 + lane) * 8];
        f32x4 acc[2];
        f32x4 z = {0.f, 0.f, 0.f, 0.f};
        acc[0] = z; acc[1] = z;
        #pragma unroll
        for (int kt = 0; kt < 4; kt++) {
            #pragma unroll
            for (int i = 0; i < 2; i++) acc[i] = MFMA16(hA[kt], B2w[i][kt], acc[i]);
        }
        #pragma unroll
        for (int i = 0; i < 2; i++) {
            int mtg = wave * 2 + i;
            float m = fmaxf(fmaxf(acc[i][0], acc[i][1]), fmaxf(acc[i][2], acc[i][3]));
            m = fmaxf(m, __shfl_xor(m, 16));
            m = fmaxf(m, __shfl_xor(m, 32));
            if (lane < 16)
                x1[(size_t)(node0 + nl) * 128 + mtg * 16 + lane] = (__bf16)(m + b2v[i]);
        }
    }
}

// =================== conv2 ===================
// 500 blocks x 512 threads x 40 nodes (NT2=10 tiles of NB2=4) -> ONE barrier
// per 4 nodes (half R6's interval count). No msgF in LDS: each producer wave
// gathers its 4-node B-frags directly to registers (20 independent uint4/lane;
// 4x redundancy across waves is L1/L2-absorbed). hidF double-buffered (64 KB).
// Consumer waves 4-7: W2 register-resident, layer2 + fused global max-pool
// with PER-NODE graph-boundary flush (1250 % 4 != 0).
#define NB2 4
#define NT2 10
__global__ __launch_bounds__(512, 2) void conv2_kernel(
    const float* __restrict__ pos, const int* __restrict__ esrc,
    const __bf16* __restrict__ x1,
    const __bf16* __restrict__ W1p, const float* __restrict__ b1,
    const __bf16* __restrict__ W2p, const float* __restrict__ b2,
    unsigned int* __restrict__ pooled)
{
    __shared__ __attribute__((aligned(16))) __bf16 hidF[2][NB2 * 8 * 64 * 8];  // 2x32 KB
    const int tid = threadIdx.x, lane = tid & 63, wave = tid >> 6;
    const int quad = lane >> 4, col = lane & 15;
    const int base = blockIdx.x * (NB2 * NT2);

    if (wave < 4) {
        // ===== producer: layer 1, B-frags in registers =====
        bf16x8 A1[4][5];
        f32x4 bias1[4];
        #pragma unroll
        for (int i = 0; i < 4; i++) {
            int mtg = wave * 4 + i;
            #pragma unroll
            for (int kt = 0; kt < 5; kt++)
                A1[i][kt] = *(const bf16x8*)&W1p[((mtg * 5 + kt) * 64 + lane) * 8];
            bias1[i] = *(const f32x4*)&b1[mtg * 16 + quad * 4];
        }

        for (int k = 0; k < NT2; k++) {
            const int buf = k & 1;
            const int n0 = base + k * NB2;
            // gather B-frags for 4 nodes (20 uint4 loads/lane, dep-depth 2)
            bf16x8 B[NB2][5];
            #pragma unroll
            for (int nl = 0; nl < NB2; nl++) {
                int d = n0 + nl;
                int s = esrc[d * 16 + col];
                #pragma unroll
                for (int kt = 0; kt < 4; kt++)
                    B[nl][kt] = *(const bf16x8*)&x1[(size_t)s * 128 + kt * 32 + quad * 8];
                bf16x8 v;
                #pragma unroll
                for (int j = 0; j < 8; j++) v[j] = (__bf16)0.f;
                if (quad == 0) {
                    v[0] = (__bf16)(pos[3*s]   - pos[3*d]);
                    v[1] = (__bf16)(pos[3*s+1] - pos[3*d+1]);
                    v[2] = (__bf16)(pos[3*s+2] - pos[3*d+2]);
                }
                B[nl][4] = v;
            }
            // layer1 -> hidF[buf]
            #pragma unroll
            for (int nl = 0; nl < NB2; nl++) {
                #pragma unroll
                for (int i = 0; i < 4; i++) {
                    int mtg = wave * 4 + i;
                    f32x4 acc = bias1[i];
                    #pragma unroll
                    for (int kt = 0; kt < 5; kt++) acc = MFMA16(A1[i][kt], B[nl][kt], acc);
                    union { __bf16 h[4]; uint2 u; } pk;
                    #pragma unroll
                    for (int r = 0; r < 4; r++) pk.h[r] = (__bf16)fmaxf(acc[r], 0.f);
                    int kt2 = mtg >> 1;
                    int lane2 = ((mtg * 2 + (quad >> 1)) & 3) * 16 + col;
                    int j0 = (quad & 1) * 4;
                    *(uint2*)&hidF[buf][((nl * 8 + kt2) * 64 + lane2) * 8 + j0] = pk.u;
                }
            }
            __syncthreads();
        }
    } else {
        // ===== consumer: layer 2 + fused global max-pool =====
        const int wv = wave - 4;
        bf16x8 A2[4][8];
        #pragma unroll
        for (int i = 0; i < 4; i++) {
            int mtg = wv * 4 + i;
            #pragma unroll
            for (int kt = 0; kt < 8; kt++)
                A2[i][kt] = *(const bf16x8*)&W2p[((mtg * 8 + kt) * 64 + lane) * 8];
        }
        f32x4 runmax[4];
        #pragma unroll
        for (int i = 0; i < 4; i++)
            #pragma unroll
            for (int r = 0; r < 4; r++) runmax[i][r] = -3.4e38f;
        int gprev = base / NPG;

        auto flushfn = [&]() {
            #pragma unroll
            for (int i = 0; i < 4; i++) {
                #pragma unroll
                for (int r = 0; r < 4; r++) {
                    float v = runmax[i][r];
                    v = fmaxf(v, __shfl_xor(v, 1));
                    v = fmaxf(v, __shfl_xor(v, 2));
                    v = fmaxf(v, __shfl_xor(v, 4));
                    v = fmaxf(v, __shfl_xor(v, 8));
                    if (col == 0) {
                        int c = (wv * 4 + i) * 16 + quad * 4 + r;
                        float val = v + b2[c];
                        unsigned u = __float_as_uint(val);
                        u = (u & 0x80000000u) ? ~u : (u | 0x80000000u);
                        atomicMax(&pooled[gprev * 256 + c], u);
                    }
                    runmax[i][r] = -3.4e38f;
                }
            }
        };
        auto consume = [&](int tk) {
            int buf1 = tk & 1;
            int n0 = base + tk * NB2;
            #pragma unroll
            for (int nl = 0; nl < NB2; nl++) {
                int g = (n0 + nl) / NPG;          // per-node boundary check
                if (g != gprev) { flushfn(); gprev = g; }
                bf16x8 hB[8];
                #pragma unroll
                for (int kt = 0; kt < 8; kt++)
                    hB[kt] = *(const bf16x8*)&hidF[buf1][((nl * 8 + kt) * 64 + lane) * 8];
                f32x4 acc[4];
                f32x4 z = {0.f, 0.f, 0.f, 0.f};
                #pragma unroll
                for (int i = 0; i < 4; i++) acc[i] = z;
                #pragma unroll
                for (int kt = 0; kt < 8; kt++) {
                    #pragma unroll
                    for (int i = 0; i < 4; i++) acc[i] = MFMA16(A2[i][kt], hB[kt], acc[i]);
                }
                #pragma unroll
                for (int i = 0; i < 4; i++)
                    #pragma unroll
                    for (int r = 0; r < 4; r++)
                        runmax[i][r] = fmaxf(runmax[i][r], acc[i][r]);
            }
        };

        for (int k = 0; k < NT2; k++) {
            if (k > 0) consume(k - 1);
            __syncthreads();
        }
        consume(NT2 - 1);
        flushfn();
    }
}

// =================== head (tiny, fp32) ===================
__global__ __launch_bounds__(256) void head_kernel(
    const unsigned int* __restrict__ pooled,
    const float* __restrict__ fc1_W, const float* __restrict__ fc1_b,
    const float* __restrict__ fc2_W, const float* __restrict__ fc2_b,
    const float* __restrict__ lab_W, const float* __restrict__ lab_b,
    const float* __restrict__ box_W, const float* __restrict__ box_b,
    float* __restrict__ out)
{
    __shared__ float p [GRAPHS][256];
    __shared__ float h1[GRAPHS][256];
    __shared__ float h2[GRAPHS][128];
    const int c = threadIdx.x;

    #pragma unroll
    for (int g = 0; g < GRAPHS; g++) {
        unsigned u = pooled[g*256 + c];
        u = (u & 0x80000000u) ? (u & 0x7fffffffu) : ~u;
        p[g][c] = __uint_as_float(u);
    }
    __syncthreads();

    float acc[GRAPHS];
    float bb = fc1_b[c];
    #pragma unroll
    for (int g = 0; g < GRAPHS; g++) acc[g] = bb;
    for (int k = 0; k < 256; k++) {
        float w = fc1_W[k*256 + c];
        #pragma unroll
        for (int g = 0; g < GRAPHS; g++) acc[g] += p[g][k] * w;
    }
    #pragma unroll
    for (int g = 0; g < GRAPHS; g++) h1[g][c] = fmaxf(acc[g], 0.0f);
    __syncthreads();

    if (c < 128) {
        float bb2 = fc2_b[c];
        #pragma unroll
        for (int g = 0; g < GRAPHS; g++) acc[g] = bb2;
        for (int k = 0; k < 256; k++) {
            float w = fc2_W[k*128 + c];
            #pragma unroll
            for (int g = 0; g < GRAPHS; g++) acc[g] += h1[g][k] * w;
        }
        #pragma unroll
        for (int g = 0; g < GRAPHS; g++) h2[g][c] = fmaxf(acc[g], 0.0f);
    }
    __syncthreads();

    if (c < 160) {
        int g = c / 10, j = c % 10;
        float a = lab_b[j];
        for (int k = 0; k < 128; k++) a += h2[g][k] * lab_W[k*10 + j];
        out[c] = a;
    } else {
        int t = c - 160;
        int g = t / 6, j = t % 6;
        float a = box_b[j];
        for (int k = 0; k < 128; k++) a += h2[g][k] * box_W[k*6 + j];
        out[160 + t] = a;
    }
}

extern "C" void kernel_launch(void* const* d_in, const int* in_sizes, int n_in,
                              void* d_out, int out_size, void* d_ws, size_t ws_size,
                              hipStream_t stream) {
    const float* pos   = (const float*)d_in[0];
    const int*   esrc  = (const int*)  d_in[1];
    const float* c1W1 = (const float*)d_in[4];
    const float* c1b1 = (const float*)d_in[5];
    const float* c1W2 = (const float*)d_in[6];
    const float* c1b2 = (const float*)d_in[7];
    const float* c2W1 = (const float*)d_in[8];
    const float* c2b1 = (const float*)d_in[9];
    const float* c2W2 = (const float*)d_in[10];
    const float* c2b2 = (const float*)d_in[11];
    const float* fc1W = (const float*)d_in[12];
    const float* fc1b = (const float*)d_in[13];
    const float* fc2W = (const float*)d_in[14];
    const float* fc2b = (const float*)d_in[15];
    const float* labW = (const float*)d_in[16];
    const float* labb = (const float*)d_in[17];
    const float* boxW = (const float*)d_in[18];
    const float* boxb = (const float*)d_in[19];

    __bf16* wsb = (__bf16*)d_ws;
    __bf16* x1  = wsb + OFF_X1;
    __bf16* p1  = wsb + OFF_P1;
    __bf16* p2  = wsb + OFF_P2;
    __bf16* p3  = wsb + OFF_P3;
    __bf16* p4  = wsb + OFF_P4;
    unsigned int* pooled = (unsigned int*)((char*)d_ws + OFF_POOL_BYTES);

    pack_weights<<<62, 256, 0, stream>>>(c1W1, c1W2, c2W1, c2W2, p1, p2, p3, p4, pooled);
    conv1_kernel<<<N_NODES / NB1, 256, 0, stream>>>(pos, esrc, p1, c1b1, p2, c1b2, x1);
    conv2_kernel<<<N_NODES / (NB2 * NT2), 512, 0, stream>>>(pos, esrc, x1, p3, c2b1, p4, c2b2, pooled);
    head_kernel<<<1, 256, 0, stream>>>(pooled, fc1W, fc1b, fc2W, fc2b,
                                       labW, labb, boxW, boxb, (float*)d_out);
}

// Round 8
// 251.796 us; speedup vs baseline: 1.1702x; 1.1702x over previous
//
#include <hip/hip_runtime.h>

#define N_NODES 20000
#define DEG 16
#define GRAPHS 16
#define NPG 1250

typedef __bf16 bf16x8 __attribute__((ext_vector_type(8)));
typedef float f32x4 __attribute__((ext_vector_type(4)));
#define MFMA16(a, b, c) __builtin_amdgcn_mfma_f32_16x16x32_bf16(a, b, c, 0, 0, 0)

// ---- workspace layout (bf16 element offsets) ----
#define OFF_X1    0            // x1 [20000][128] bf16
#define OFF_P1    2560000      // c1W1 packed: MT=8  KT=1 -> 4096
#define OFF_P2    2564096      // c1W2 packed: MT=8  KT=4 -> 16384
#define OFF_P3    2580480      // c2W1 packed: MT=16 KT=5 -> 40960
#define OFF_P4    2621440      // c2W2 packed: MT=16 KT=8 -> 65536
#define OFF_POOL_BYTES 5373952 // pooled u32[16*256]

// Frag layout (A-role == B-role for mfma_f32_16x16x32_bf16):
//   frag[((t*KT+kt)*64+lane)*8 + j] = X[k = kt*32 + (lane>>4)*8 + j][idx = lane&15]
__global__ __launch_bounds__(256) void pack_weights(
    const float* __restrict__ c1W1, const float* __restrict__ c1W2,
    const float* __restrict__ c2W1, const float* __restrict__ c2W2,
    __bf16* __restrict__ p1, __bf16* __restrict__ p2,
    __bf16* __restrict__ p3, __bf16* __restrict__ p4,
    unsigned int* __restrict__ pooled)
{
    int t = blockIdx.x * 256 + threadIdx.x;
    if (t < GRAPHS * 256) pooled[t] = 0u;   // flipped(-inf) == 0
    if (t >= 15872) return;
    const float* W; __bf16* out; int M, Kreal, KT, grp;
    if      (t <  512)  { W = c1W1; out = p1; M = 128; Kreal =   6; KT = 1; grp = t; }
    else if (t < 2560)  { W = c1W2; out = p2; M = 128; Kreal = 128; KT = 4; grp = t - 512; }
    else if (t < 7680)  { W = c2W1; out = p3; M = 256; Kreal = 131; KT = 5; grp = t - 2560; }
    else                { W = c2W2; out = p4; M = 256; Kreal = 256; KT = 8; grp = t - 7680; }
    int lane = grp & 63, rest = grp >> 6;
    int kt = rest % KT, mt = rest / KT;
    int m = mt * 16 + (lane & 15);
    int kbase = kt * 32 + ((lane >> 4) << 3);
    bf16x8 v;
    #pragma unroll
    for (int j = 0; j < 8; j++) {
        int k = kbase + j;
        v[j] = (k < Kreal) ? (__bf16)W[k * M + m] : (__bf16)0.f;
    }
    *(bf16x8*)&out[grp * 8] = v;
}

// =================== conv1 ===================
// 1250 blocks x 16 nodes. Phase 0: 256 threads = 256 edges, one fully-parallel
// gather each -> msgF (4 KB). Phase 1: quad0-masked ds_read B-frag, MFMA.
// Phase 2: D[edge][ch], edge-max, write x1.
#define NB1 16
__global__ __launch_bounds__(256, 2) void conv1_kernel(
    const float* __restrict__ pos, const int* __restrict__ esrc,
    const __bf16* __restrict__ W1p, const float* __restrict__ b1,
    const __bf16* __restrict__ W2p, const float* __restrict__ b2,
    __bf16* __restrict__ x1)
{
    __shared__ __attribute__((aligned(16))) __bf16 msgF[NB1][16][8];        // 4 KB
    __shared__ __attribute__((aligned(16))) __bf16 hidF[NB1 * 4 * 64 * 8];  // 64 KB
    const int tid = threadIdx.x, lane = tid & 63, wave = tid >> 6;
    const int quad = lane >> 4, col = lane & 15;
    const int node0 = blockIdx.x * NB1;

    bf16x8 A1[2], B2w[2][4];
    f32x4 bias1[2];
    float b2v[2];
    #pragma unroll
    for (int i = 0; i < 2; i++) {
        int mtg = wave * 2 + i;
        A1[i] = *(const bf16x8*)&W1p[(mtg * 64 + lane) * 8];
        bias1[i] = *(const f32x4*)&b1[mtg * 16 + quad * 4];
        #pragma unroll
        for (int kt = 0; kt < 4; kt++)
            B2w[i][kt] = *(const bf16x8*)&W2p[((mtg * 4 + kt) * 64 + lane) * 8];
        b2v[i] = b2[mtg * 16 + col];
    }

    // ---- phase 0: fully-parallel gather, one edge per thread ----
    {
        int nl = tid >> 4, e = tid & 15;
        int d = node0 + nl;
        int s = esrc[d * 16 + e];
        float sx = pos[3*s], sy = pos[3*s+1], sz = pos[3*s+2];
        float dx = pos[3*d], dy = pos[3*d+1], dz = pos[3*d+2];
        bf16x8 v;
        v[0] = (__bf16)sx; v[1] = (__bf16)sy; v[2] = (__bf16)sz;
        v[3] = (__bf16)(sx - dx); v[4] = (__bf16)(sy - dy); v[5] = (__bf16)(sz - dz);
        v[6] = (__bf16)0.f; v[7] = (__bf16)0.f;
        *(bf16x8*)&msgF[nl][e][0] = v;
    }
    __syncthreads();

    // ---- phase 1: layer1 MFMA, write hid frags ----
    #pragma unroll
    for (int nl = 0; nl < NB1; nl++) {
        bf16x8 B;
        if (quad == 0) {
            B = *(const bf16x8*)&msgF[nl][col][0];
        } else {
            #pragma unroll
            for (int j = 0; j < 8; j++) B[j] = (__bf16)0.f;
        }
        #pragma unroll
        for (int i = 0; i < 2; i++) {
            int mtg = wave * 2 + i;
            f32x4 acc = bias1[i];
            acc = MFMA16(A1[i], B, acc);
            union { __bf16 h[4]; uint2 u; } pk;
            #pragma unroll
            for (int r = 0; r < 4; r++) pk.h[r] = (__bf16)fmaxf(acc[r], 0.f);
            int kt2 = mtg >> 1;
            int lane2 = ((mtg * 2 + (quad >> 1)) & 3) * 16 + col;
            int j0 = (quad & 1) * 4;
            *(uint2*)&hidF[((nl * 4 + kt2) * 64 + lane2) * 8 + j0] = pk.u;
        }
    }
    __syncthreads();

    // ---- phase 2: D[edge][ch], edge-max, write x1 ----
    #pragma unroll
    for (int nl = 0; nl < NB1; nl++) {
        bf16x8 hA[4];
        #pragma unroll
        for (int kt = 0; kt < 4; kt++)
            hA[kt] = *(const bf16x8*)&hidF[((nl * 4 + kt) * 64 + lane) * 8];
        f32x4 acc[2];
        f32x4 z = {0.f, 0.f, 0.f, 0.f};
        acc[0] = z; acc[1] = z;
        #pragma unroll
        for (int kt = 0; kt < 4; kt++) {
            #pragma unroll
            for (int i = 0; i < 2; i++) acc[i] = MFMA16(hA[kt], B2w[i][kt], acc[i]);
        }
        #pragma unroll
        for (int i = 0; i < 2; i++) {
            int mtg = wave * 2 + i;
            float m = fmaxf(fmaxf(acc[i][0], acc[i][1]), fmaxf(acc[i][2], acc[i][3]));
            m = fmaxf(m, __shfl_xor(m, 16));
            m = fmaxf(m, __shfl_xor(m, 32));
            if (lane < 16)
                x1[(size_t)(node0 + nl) * 128 + mtg * 16 + lane] = (__bf16)(m + b2v[i]);
        }
    }
}

// =================== conv2 ===================
// 500 blocks x 512 threads x 40 nodes (NT2=20 tiles of NB2=2), UNIFIED waves:
// every wave does BOTH layers for 2 of 16 channel-tiles. Resident/wave:
// A1[2][5]=40 + W2-B[2][8]=64 + bias = ~120 VGPR. amdgpu_waves_per_eu(2,2)
// forces a 256-VGPR budget so the allocator actually KEEPS them (R3-R7 all ran
// at VGPR~105 < sizeof(resident arrays): compiler rematerialized weight loads
// inside the node loop = the ~3k cyc/node latency disease).
// Layer2 in D[edge][ch] orientation (A=hid frag, B=W2 frag — same packed data,
// A/B layouts identical): runmax accumulates raw D across nodes; single
// shuffle-reduce + bias only at graph flush.
#define NB2 2
#define NT2 20
__global__ __launch_bounds__(512) __attribute__((amdgpu_waves_per_eu(2, 2)))
void conv2_kernel(
    const float* __restrict__ pos, const int* __restrict__ esrc,
    const __bf16* __restrict__ x1,
    const __bf16* __restrict__ W1p, const float* __restrict__ b1,
    const __bf16* __restrict__ W2p, const float* __restrict__ b2,
    unsigned int* __restrict__ pooled)
{
    __shared__ __attribute__((aligned(16))) __bf16 msgF[2][NB2 * 5 * 64 * 8];  // 2x10 KB
    __shared__ __attribute__((aligned(16))) __bf16 hidF[2][NB2 * 8 * 64 * 8];  // 2x16 KB
    const int tid = threadIdx.x, lane = tid & 63, wave = tid >> 6;
    const int quad = lane >> 4, col = lane & 15;
    const int base = blockIdx.x * (NB2 * NT2);

    // resident weights: layer1 A-frags (2 mtiles x 5 kt), layer2 B-frags (2 ntiles x 8 kt)
    bf16x8 A1[2][5], B2r[2][8];
    f32x4 bias1[2];
    #pragma unroll
    for (int i = 0; i < 2; i++) {
        int tg = wave * 2 + i;
        #pragma unroll
        for (int kt = 0; kt < 5; kt++)
            A1[i][kt] = *(const bf16x8*)&W1p[((tg * 5 + kt) * 64 + lane) * 8];
        #pragma unroll
        for (int kt = 0; kt < 8; kt++)
            B2r[i][kt] = *(const bf16x8*)&W2p[((tg * 8 + kt) * 64 + lane) * 8];
        bias1[i] = *(const f32x4*)&b1[tg * 16 + quad * 4];
    }

    f32x4 runmax[2];
    #pragma unroll
    for (int i = 0; i < 2; i++)
        #pragma unroll
        for (int r = 0; r < 4; r++) runmax[i][r] = -3.4e38f;
    int gprev = base / NPG;

    auto stage = [&](int n0, int buf) {
        #pragma unroll
        for (int s = 0; s < 2; s++) {
            int u = tid + 512 * s;
            if (u < NB2 * 5 * 64) {
                int nl = u / 320, rr = u % 320;
                int kt = rr >> 6, l = rr & 63;
                int q = l >> 4, c = l & 15;
                int d = n0 + nl;
                if (kt < 4) {
                    int src = esrc[d * 16 + c];
                    *(uint4*)&msgF[buf][((nl * 5 + kt) * 64 + l) * 8] =
                        *(const uint4*)&x1[(size_t)src * 128 + kt * 32 + q * 8];
                } else {
                    bf16x8 v;
                    #pragma unroll
                    for (int j = 0; j < 8; j++) v[j] = (__bf16)0.f;
                    if (q == 0) {
                        int src = esrc[d * 16 + c];
                        v[0] = (__bf16)(pos[3*src]   - pos[3*d]);
                        v[1] = (__bf16)(pos[3*src+1] - pos[3*d+1]);
                        v[2] = (__bf16)(pos[3*src+2] - pos[3*d+2]);
                    }
                    *(bf16x8*)&msgF[buf][((nl * 5 + kt) * 64 + l) * 8] = v;
                }
            }
        }
    };

    auto flushfn = [&]() {
        #pragma unroll
        for (int i = 0; i < 2; i++) {
            float v = fmaxf(fmaxf(runmax[i][0], runmax[i][1]),
                            fmaxf(runmax[i][2], runmax[i][3]));
            v = fmaxf(v, __shfl_xor(v, 16));
            v = fmaxf(v, __shfl_xor(v, 32));
            if (lane < 16) {
                int c = (wave * 2 + i) * 16 + lane;
                float val = v + b2[c];
                unsigned u = __float_as_uint(val);
                u = (u & 0x80000000u) ? ~u : (u | 0x80000000u);
                atomicMax(&pooled[gprev * 256 + c], u);
            }
            #pragma unroll
            for (int r = 0; r < 4; r++) runmax[i][r] = -3.4e38f;
        }
    };

    auto consume = [&](int tk) {     // layer2 for tile tk from hidF[tk&1]
        int buf1 = tk & 1;
        int n0 = base + tk * NB2;
        #pragma unroll
        for (int nl = 0; nl < NB2; nl++) {
            int g = (n0 + nl) / NPG;
            if (g != gprev) { flushfn(); gprev = g; }
            bf16x8 hA[8];
            #pragma unroll
            for (int kt = 0; kt < 8; kt++)
                hA[kt] = *(const bf16x8*)&hidF[buf1][((nl * 8 + kt) * 64 + lane) * 8];
            f32x4 acc[2];
            f32x4 z = {0.f, 0.f, 0.f, 0.f};
            acc[0] = z; acc[1] = z;
            #pragma unroll
            for (int kt = 0; kt < 8; kt++) {
                #pragma unroll
                for (int i = 0; i < 2; i++) acc[i] = MFMA16(hA[kt], B2r[i][kt], acc[i]);
            }
            #pragma unroll
            for (int i = 0; i < 2; i++)
                #pragma unroll
                for (int r = 0; r < 4; r++)
                    runmax[i][r] = fmaxf(runmax[i][r], acc[i][r]);
        }
    };

    stage(base, 0);
    __syncthreads();

    for (int k = 0; k < NT2; k++) {
        const int buf = k & 1;
        if (k + 1 < NT2) stage(base + (k + 1) * NB2, buf ^ 1);
        // layer1 tile k: msgF[buf] -> hidF[buf]
        #pragma unroll
        for (int nl = 0; nl < NB2; nl++) {
            bf16x8 B[5];
            #pragma unroll
            for (int kt = 0; kt < 5; kt++)
                B[kt] = *(const bf16x8*)&msgF[buf][((nl * 5 + kt) * 64 + lane) * 8];
            #pragma unroll
            for (int i = 0; i < 2; i++) {
                int mtg = wave * 2 + i;
                f32x4 acc = bias1[i];
                #pragma unroll
                for (int kt = 0; kt < 5; kt++) acc = MFMA16(A1[i][kt], B[kt], acc);
                union { __bf16 h[4]; uint2 u; } pk;
                #pragma unroll
                for (int r = 0; r < 4; r++) pk.h[r] = (__bf16)fmaxf(acc[r], 0.f);
                int kt2 = mtg >> 1;
                int lane2 = ((mtg * 2 + (quad >> 1)) & 3) * 16 + col;
                int j0 = (quad & 1) * 4;
                *(uint2*)&hidF[buf][((nl * 8 + kt2) * 64 + lane2) * 8 + j0] = pk.u;
            }
        }
        if (k > 0) consume(k - 1);
        __syncthreads();
    }
    consume(NT2 - 1);
    flushfn();
}

// =================== head (tiny, fp32) ===================
__global__ __launch_bounds__(256) void head_kernel(
    const unsigned int* __restrict__ pooled,
    const float* __restrict__ fc1_W, const float* __restrict__ fc1_b,
    const float* __restrict__ fc2_W, const float* __restrict__ fc2_b,
    const float* __restrict__ lab_W, const float* __restrict__ lab_b,
    const float* __restrict__ box_W, const float* __restrict__ box_b,
    float* __restrict__ out)
{
    __shared__ float p [GRAPHS][256];
    __shared__ float h1[GRAPHS][256];
    __shared__ float h2[GRAPHS][128];
    const int c = threadIdx.x;

    #pragma unroll
    for (int g = 0; g < GRAPHS; g++) {
        unsigned u = pooled[g*256 + c];
        u = (u & 0x80000000u) ? (u & 0x7fffffffu) : ~u;
        p[g][c] = __uint_as_float(u);
    }
    __syncthreads();

    float acc[GRAPHS];
    float bb = fc1_b[c];
    #pragma unroll
    for (int g = 0; g < GRAPHS; g++) acc[g] = bb;
    for (int k = 0; k < 256; k++) {
        float w = fc1_W[k*256 + c];
        #pragma unroll
        for (int g = 0; g < GRAPHS; g++) acc[g] += p[g][k] * w;
    }
    #pragma unroll
    for (int g = 0; g < GRAPHS; g++) h1[g][c] = fmaxf(acc[g], 0.0f);
    __syncthreads();

    if (c < 128) {
        float bb2 = fc2_b[c];
        #pragma unroll
        for (int g = 0; g < GRAPHS; g++) acc[g] = bb2;
        for (int k = 0; k < 256; k++) {
            float w = fc2_W[k*128 + c];
            #pragma unroll
            for (int g = 0; g < GRAPHS; g++) acc[g] += h1[g][k] * w;
        }
        #pragma unroll
        for (int g = 0; g < GRAPHS; g++) h2[g][c] = fmaxf(acc[g], 0.0f);
    }
    __syncthreads();

    if (c < 160) {
        int g = c / 10, j = c % 10;
        float a = lab_b[j];
        for (int k = 0; k < 128; k++) a += h2[g][k] * lab_W[k*10 + j];
        out[c] = a;
    } else {
        int t = c - 160;
        int g = t / 6, j = t % 6;
        float a = box_b[j];
        for (int k = 0; k < 128; k++) a += h2[g][k] * box_W[k*6 + j];
        out[160 + t] = a;
    }
}

extern "C" void kernel_launch(void* const* d_in, const int* in_sizes, int n_in,
                              void* d_out, int out_size, void* d_ws, size_t ws_size,
                              hipStream_t stream) {
    const float* pos   = (const float*)d_in[0];
    const int*   esrc  = (const int*)  d_in[1];
    const float* c1W1 = (const float*)d_in[4];
    const float* c1b1 = (const float*)d_in[5];
    const float* c1W2 = (const float*)d_in[6];
    const float* c1b2 = (const float*)d_in[7];
    const float* c2W1 = (const float*)d_in[8];
    const float* c2b1 = (const float*)d_in[9];
    const float* c2W2 = (const float*)d_in[10];
    const float* c2b2 = (const float*)d_in[11];
    const float* fc1W = (const float*)d_in[12];
    const float* fc1b = (const float*)d_in[13];
    const float* fc2W = (const float*)d_in[14];
    const float* fc2b = (const float*)d_in[15];
    const float* labW = (const float*)d_in[16];
    const float* labb = (const float*)d_in[17];
    const float* boxW = (const float*)d_in[18];
    const float* boxb = (const float*)d_in[19];

    __bf16* wsb = (__bf16*)d_ws;
    __bf16* x1  = wsb + OFF_X1;
    __bf16* p1  = wsb + OFF_P1;
    __bf16* p2  = wsb + OFF_P2;
    __bf16* p3  = wsb + OFF_P3;
    __bf16* p4  = wsb + OFF_P4;
    unsigned int* pooled = (unsigned int*)((char*)d_ws + OFF_POOL_BYTES);

    pack_weights<<<62, 256, 0, stream>>>(c1W1, c1W2, c2W1, c2W2, p1, p2, p3, p4, pooled);
    conv1_kernel<<<N_NODES / NB1, 256, 0, stream>>>(pos, esrc, p1, c1b1, p2, c1b2, x1);
    conv2_kernel<<<N_NODES / (NB2 * NT2), 512, 0, stream>>>(pos, esrc, x1, p3, c2b1, p4, c2b2, pooled);
    head_kernel<<<1, 256, 0, stream>>>(pooled, fc1W, fc1b, fc2W, fc2b,
                                       labW, labb, boxW, boxb, (float*)d_out);
}

// Round 9
// 241.438 us; speedup vs baseline: 1.2204x; 1.0429x over previous
//
#include <hip/hip_runtime.h>

#define N_NODES 20000
#define DEG 16
#define GRAPHS 16
#define NPG 1250

typedef __bf16 bf16x8 __attribute__((ext_vector_type(8)));
typedef float f32x4 __attribute__((ext_vector_type(4)));
#define MFMA16(a, b, c) __builtin_amdgcn_mfma_f32_16x16x32_bf16(a, b, c, 0, 0, 0)

// async global->LDS direct copy, 16 B per lane; LDS dest = uniform base + lane*16
__device__ __forceinline__ void async16(void* lds, const void* g) {
    __builtin_amdgcn_global_load_lds(
        (const __attribute__((address_space(1))) unsigned int*)(g),
        (__attribute__((address_space(3))) unsigned int*)(lds), 16, 0, 0);
}

// ---- workspace layout (bf16 element offsets) ----
#define OFF_X1    0            // x1 [20000][128] bf16
#define OFF_P1    2560000      // c1W1 packed: MT=8  KT=1 -> 4096
#define OFF_P2    2564096      // c1W2 packed: MT=8  KT=4 -> 16384
#define OFF_P3    2580480      // c2W1 packed: MT=16 KT=5 -> 40960
#define OFF_P4    2621440      // c2W2 packed: MT=16 KT=8 -> 65536
#define OFF_POOL_BYTES 5373952 // pooled u32[16*256] -> ends byte 5390336
#define OFF_RELE  2695176      // relE rows of 8 bf16: row (d*16+e) = {rel0,rel1,rel2,0..}
#define RELZ_ROW  320000       //   row 320000 = zeros (written by pack_weights)

// Frag layout (A-role == B-role for mfma_f32_16x16x32_bf16):
//   frag[((t*KT+kt)*64+lane)*8 + j] = X[k = kt*32 + (lane>>4)*8 + j][idx = lane&15]
__global__ __launch_bounds__(256) void pack_weights(
    const float* __restrict__ c1W1, const float* __restrict__ c1W2,
    const float* __restrict__ c2W1, const float* __restrict__ c2W2,
    __bf16* __restrict__ p1, __bf16* __restrict__ p2,
    __bf16* __restrict__ p3, __bf16* __restrict__ p4,
    unsigned int* __restrict__ pooled, __bf16* __restrict__ relE)
{
    int t = blockIdx.x * 256 + threadIdx.x;
    if (t < GRAPHS * 256) pooled[t] = 0u ? 0u : 0u;   // (kept simple below)
    if (t < GRAPHS * 256) pooled[t] = 0u;             // flipped(-inf) == 0
    if (t == 0) {                                     // zero row for conv2 kt=4 filler lanes
        bf16x8 z;
        #pragma unroll
        for (int j = 0; j < 8; j++) z[j] = (__bf16)0.f;
        *(bf16x8*)&relE[(size_t)RELZ_ROW * 8] = z;
    }
    if (t >= 15872) return;
    const float* W; __bf16* out; int M, Kreal, KT, grp;
    if      (t <  512)  { W = c1W1; out = p1; M = 128; Kreal =   6; KT = 1; grp = t; }
    else if (t < 2560)  { W = c1W2; out = p2; M = 128; Kreal = 128; KT = 4; grp = t - 512; }
    else if (t < 7680)  { W = c2W1; out = p3; M = 256; Kreal = 131; KT = 5; grp = t - 2560; }
    else                { W = c2W2; out = p4; M = 256; Kreal = 256; KT = 8; grp = t - 7680; }
    int lane = grp & 63, rest = grp >> 6;
    int kt = rest % KT, mt = rest / KT;
    int m = mt * 16 + (lane & 15);
    int kbase = kt * 32 + ((lane >> 4) << 3);
    bf16x8 v;
    #pragma unroll
    for (int j = 0; j < 8; j++) {
        int k = kbase + j;
        v[j] = (k < Kreal) ? (__bf16)W[k * M + m] : (__bf16)0.f;
    }
    *(bf16x8*)&out[grp * 8] = v;
}

// =================== conv1 ===================
// 1250 blocks x 16 nodes. Phase 0: 256 threads = 256 edges, fully-parallel
// gather -> msgF + relE (rel rows reused by conv2's async staging).
#define NB1 16
__global__ __launch_bounds__(256, 2) void conv1_kernel(
    const float* __restrict__ pos, const int* __restrict__ esrc,
    const __bf16* __restrict__ W1p, const float* __restrict__ b1,
    const __bf16* __restrict__ W2p, const float* __restrict__ b2,
    __bf16* __restrict__ x1, __bf16* __restrict__ relE)
{
    __shared__ __attribute__((aligned(16))) __bf16 msgF[NB1][16][8];        // 4 KB
    __shared__ __attribute__((aligned(16))) __bf16 hidF[NB1 * 4 * 64 * 8];  // 64 KB
    const int tid = threadIdx.x, lane = tid & 63, wave = tid >> 6;
    const int quad = lane >> 4, col = lane & 15;
    const int node0 = blockIdx.x * NB1;

    bf16x8 A1[2], B2w[2][4];
    f32x4 bias1[2];
    float b2v[2];
    #pragma unroll
    for (int i = 0; i < 2; i++) {
        int mtg = wave * 2 + i;
        A1[i] = *(const bf16x8*)&W1p[(mtg * 64 + lane) * 8];
        bias1[i] = *(const f32x4*)&b1[mtg * 16 + quad * 4];
        #pragma unroll
        for (int kt = 0; kt < 4; kt++)
            B2w[i][kt] = *(const bf16x8*)&W2p[((mtg * 4 + kt) * 64 + lane) * 8];
        b2v[i] = b2[mtg * 16 + col];
    }

    // ---- phase 0: fully-parallel gather, one edge per thread ----
    {
        int nl = tid >> 4, e = tid & 15;
        int d = node0 + nl;
        int s = esrc[d * 16 + e];
        float sx = pos[3*s], sy = pos[3*s+1], sz = pos[3*s+2];
        float dx = pos[3*d], dy = pos[3*d+1], dz = pos[3*d+2];
        __bf16 rx = (__bf16)(sx - dx), ry = (__bf16)(sy - dy), rz = (__bf16)(sz - dz);
        bf16x8 v;
        v[0] = (__bf16)sx; v[1] = (__bf16)sy; v[2] = (__bf16)sz;
        v[3] = rx; v[4] = ry; v[5] = rz;
        v[6] = (__bf16)0.f; v[7] = (__bf16)0.f;
        *(bf16x8*)&msgF[nl][e][0] = v;
        bf16x8 rv;
        rv[0] = rx; rv[1] = ry; rv[2] = rz;
        #pragma unroll
        for (int j = 3; j < 8; j++) rv[j] = (__bf16)0.f;
        *(bf16x8*)&relE[((size_t)d * 16 + e) * 8] = rv;   // conv2 staging source
    }
    __syncthreads();

    // ---- phase 1: layer1 MFMA, write hid frags ----
    #pragma unroll
    for (int nl = 0; nl < NB1; nl++) {
        bf16x8 B;
        if (quad == 0) {
            B = *(const bf16x8*)&msgF[nl][col][0];
        } else {
            #pragma unroll
            for (int j = 0; j < 8; j++) B[j] = (__bf16)0.f;
        }
        #pragma unroll
        for (int i = 0; i < 2; i++) {
            int mtg = wave * 2 + i;
            f32x4 acc = bias1[i];
            acc = MFMA16(A1[i], B, acc);
            union { __bf16 h[4]; uint2 u; } pk;
            #pragma unroll
            for (int r = 0; r < 4; r++) pk.h[r] = (__bf16)fmaxf(acc[r], 0.f);
            int kt2 = mtg >> 1;
            int lane2 = ((mtg * 2 + (quad >> 1)) & 3) * 16 + col;
            int j0 = (quad & 1) * 4;
            *(uint2*)&hidF[((nl * 4 + kt2) * 64 + lane2) * 8 + j0] = pk.u;
        }
    }
    __syncthreads();

    // ---- phase 2: D[edge][ch], edge-max, write x1 ----
    #pragma unroll
    for (int nl = 0; nl < NB1; nl++) {
        bf16x8 hA[4];
        #pragma unroll
        for (int kt = 0; kt < 4; kt++)
            hA[kt] = *(const bf16x8*)&hidF[((nl * 4 + kt) * 64 + lane) * 8];
        f32x4 acc[2];
        f32x4 z = {0.f, 0.f, 0.f, 0.f};
        acc[0] = z; acc[1] = z;
        #pragma unroll
        for (int kt = 0; kt < 4; kt++) {
            #pragma unroll
            for (int i = 0; i < 2; i++) acc[i] = MFMA16(hA[kt], B2w[i][kt], acc[i]);
        }
        #pragma unroll
        for (int i = 0; i < 2; i++) {
            int mtg = wave * 2 + i;
            float m = fmaxf(fmaxf(acc[i][0], acc[i][1]), fmaxf(acc[i][2], acc[i][3]));
            m = fmaxf(m, __shfl_xor(m, 16));
            m = fmaxf(m, __shfl_xor(m, 32));
            if (lane < 16)
                x1[(size_t)(node0 + nl) * 128 + mtg * 16 + lane] = (__bf16)(m + b2v[i]);
        }
    }
}

// =================== conv2 ===================
// 500 blocks x 512 threads x 40 nodes (NT2=20 tiles of NB2=2), unified waves
// (each wave: 2 channel-tiles, both layers; weights resident in VGPR/AGPR).
// Staging is now PURE ASYNC: per tile each wave issues ONE global_load_lds
// (16 B/lane) per owned group — x1 rows for kt<4 groups, relE rows (precomputed
// by conv1) for the kt=4 group; zero-row filler for q>0 lanes. Edge indices
// pre-staged to LDS once per block. No per-tile vmcnt wait: the tile barrier
// drains the DMA after ~a full tile of MFMA has covered the latency.
#define NB2 2
#define NT2 20
__global__ __launch_bounds__(512) __attribute__((amdgpu_waves_per_eu(2, 2)))
void conv2_kernel(
    const int* __restrict__ esrc,
    const __bf16* __restrict__ x1, const __bf16* __restrict__ relE,
    const __bf16* __restrict__ W1p, const float* __restrict__ b1,
    const __bf16* __restrict__ W2p, const float* __restrict__ b2,
    unsigned int* __restrict__ pooled)
{
    __shared__ __attribute__((aligned(16))) __bf16 msgF[2][NB2 * 5 * 64 * 8];  // 2x10 KB
    __shared__ __attribute__((aligned(16))) __bf16 hidF[2][NB2 * 8 * 64 * 8];  // 2x16 KB
    __shared__ int sSrc[NB2 * NT2 * 16];                                       // 2.56 KB
    const int tid = threadIdx.x, lane = tid & 63, wave = tid >> 6;
    const int quad = lane >> 4, col = lane & 15;
    const int base = blockIdx.x * (NB2 * NT2);

    // edge-index table for the whole block (coalesced, once)
    for (int u = tid; u < NB2 * NT2 * 16; u += 512) sSrc[u] = esrc[base * 16 + u];

    // resident weights: layer1 A-frags (2 mtiles x 5 kt), layer2 B-frags (2 ntiles x 8 kt)
    bf16x8 A1[2][5], B2r[2][8];
    f32x4 bias1[2];
    #pragma unroll
    for (int i = 0; i < 2; i++) {
        int tg = wave * 2 + i;
        #pragma unroll
        for (int kt = 0; kt < 5; kt++)
            A1[i][kt] = *(const bf16x8*)&W1p[((tg * 5 + kt) * 64 + lane) * 8];
        #pragma unroll
        for (int kt = 0; kt < 8; kt++)
            B2r[i][kt] = *(const bf16x8*)&W2p[((tg * 8 + kt) * 64 + lane) * 8];
        bias1[i] = *(const f32x4*)&b1[tg * 16 + quad * 4];
    }

    f32x4 runmax[2];
    #pragma unroll
    for (int i = 0; i < 2; i++)
        #pragma unroll
        for (int r = 0; r < 4; r++) runmax[i][r] = -3.4e38f;
    int gprev = base / NPG;

    // stage tile tk into msgF[tk&1]: one async16 per owned group
    auto stage = [&](int tk) {
        int buf = tk & 1;
        #pragma unroll
        for (int s = 0; s < 2; s++) {
            int g = wave + 8 * s;
            if (g < 10) {
                int nl = g / 5, kt = g % 5;
                __bf16* ldst = &msgF[buf][g * 64 * 8];   // + lane*16 implicit
                const __bf16* gsrc;
                if (kt < 4) {
                    int src = sSrc[(tk * NB2 + nl) * 16 + col];
                    gsrc = &x1[(size_t)src * 128 + kt * 32 + quad * 8];
                } else {
                    int row = (quad == 0) ? ((base + tk * NB2 + nl) * 16 + col) : RELZ_ROW;
                    gsrc = &relE[(size_t)row * 8];
                }
                async16(ldst, gsrc);
            }
        }
    };

    auto flushfn = [&]() {
        #pragma unroll
        for (int i = 0; i < 2; i++) {
            float v = fmaxf(fmaxf(runmax[i][0], runmax[i][1]),
                            fmaxf(runmax[i][2], runmax[i][3]));
            v = fmaxf(v, __shfl_xor(v, 16));
            v = fmaxf(v, __shfl_xor(v, 32));
            if (lane < 16) {
                int c = (wave * 2 + i) * 16 + lane;
                float val = v + b2[c];
                unsigned u = __float_as_uint(val);
                u = (u & 0x80000000u) ? ~u : (u | 0x80000000u);
                atomicMax(&pooled[gprev * 256 + c], u);
            }
            #pragma unroll
            for (int r = 0; r < 4; r++) runmax[i][r] = -3.4e38f;
        }
    };

    auto consume = [&](int tk) {     // layer2 for tile tk from hidF[tk&1]
        int buf1 = tk & 1;
        int n0 = base + tk * NB2;
        #pragma unroll
        for (int nl = 0; nl < NB2; nl++) {
            int g = (n0 + nl) / NPG;
            if (g != gprev) { flushfn(); gprev = g; }
            bf16x8 hA[8];
            #pragma unroll
            for (int kt = 0; kt < 8; kt++)
                hA[kt] = *(const bf16x8*)&hidF[buf1][((nl * 8 + kt) * 64 + lane) * 8];
            f32x4 acc[2];
            f32x4 z = {0.f, 0.f, 0.f, 0.f};
            acc[0] = z; acc[1] = z;
            #pragma unroll
            for (int kt = 0; kt < 8; kt++) {
                #pragma unroll
                for (int i = 0; i < 2; i++) acc[i] = MFMA16(hA[kt], B2r[i][kt], acc[i]);
            }
            #pragma unroll
            for (int i = 0; i < 2; i++)
                #pragma unroll
                for (int r = 0; r < 4; r++)
                    runmax[i][r] = fmaxf(runmax[i][r], acc[i][r]);
        }
    };

    __syncthreads();                 // sSrc visible to all waves
    stage(0);
    __syncthreads();                 // drain tile-0 DMA

    for (int k = 0; k < NT2; k++) {
        const int buf = k & 1;
        if (k + 1 < NT2) stage(k + 1);       // async issue; drained at loop barrier
        // layer1 tile k: msgF[buf] -> hidF[buf]
        #pragma unroll
        for (int nl = 0; nl < NB2; nl++) {
            bf16x8 B[5];
            #pragma unroll
            for (int kt = 0; kt < 5; kt++)
                B[kt] = *(const bf16x8*)&msgF[buf][((nl * 5 + kt) * 64 + lane) * 8];
            #pragma unroll
            for (int i = 0; i < 2; i++) {
                int mtg = wave * 2 + i;
                f32x4 acc = bias1[i];
                #pragma unroll
                for (int kt = 0; kt < 5; kt++) acc = MFMA16(A1[i][kt], B[kt], acc);
                union { __bf16 h[4]; uint2 u; } pk;
                #pragma unroll
                for (int r = 0; r < 4; r++) pk.h[r] = (__bf16)fmaxf(acc[r], 0.f);
                int kt2 = mtg >> 1;
                int lane2 = ((mtg * 2 + (quad >> 1)) & 3) * 16 + col;
                int j0 = (quad & 1) * 4;
                *(uint2*)&hidF[buf][((nl * 8 + kt2) * 64 + lane2) * 8 + j0] = pk.u;
            }
        }
        if (k > 0) consume(k - 1);
        __syncthreads();
    }
    consume(NT2 - 1);
    flushfn();
}

// =================== head (tiny, fp32) ===================
__global__ __launch_bounds__(256) void head_kernel(
    const unsigned int* __restrict__ pooled,
    const float* __restrict__ fc1_W, const float* __restrict__ fc1_b,
    const float* __restrict__ fc2_W, const float* __restrict__ fc2_b,
    const float* __restrict__ lab_W, const float* __restrict__ lab_b,
    const float* __restrict__ box_W, const float* __restrict__ box_b,
    float* __restrict__ out)
{
    __shared__ float p [GRAPHS][256];
    __shared__ float h1[GRAPHS][256];
    __shared__ float h2[GRAPHS][128];
    const int c = threadIdx.x;

    #pragma unroll
    for (int g = 0; g < GRAPHS; g++) {
        unsigned u = pooled[g*256 + c];
        u = (u & 0x80000000u) ? (u & 0x7fffffffu) : ~u;
        p[g][c] = __uint_as_float(u);
    }
    __syncthreads();

    float acc[GRAPHS];
    float bb = fc1_b[c];
    #pragma unroll
    for (int g = 0; g < GRAPHS; g++) acc[g] = bb;
    for (int k = 0; k < 256; k++) {
        float w = fc1_W[k*256 + c];
        #pragma unroll
        for (int g = 0; g < GRAPHS; g++) acc[g] += p[g][k] * w;
    }
    #pragma unroll
    for (int g = 0; g < GRAPHS; g++) h1[g][c] = fmaxf(acc[g], 0.0f);
    __syncthreads();

    if (c < 128) {
        float bb2 = fc2_b[c];
        #pragma unroll
        for (int g = 0; g < GRAPHS; g++) acc[g] = bb2;
        for (int k = 0; k < 256; k++) {
            float w = fc2_W[k*128 + c];
            #pragma unroll
            for (int g = 0; g < GRAPHS; g++) acc[g] += h1[g][k] * w;
        }
        #pragma unroll
        for (int g = 0; g < GRAPHS; g++) h2[g][c] = fmaxf(acc[g], 0.0f);
    }
    __syncthreads();

    if (c < 160) {
        int g = c / 10, j = c % 10;
        float a = lab_b[j];
        for (int k = 0; k < 128; k++) a += h2[g][k] * lab_W[k*10 + j];
        out[c] = a;
    } else {
        int t = c - 160;
        int g = t / 6, j = t % 6;
        float a = box_b[j];
        for (int k = 0; k < 128; k++) a += h2[g][k] * box_W[k*6 + j];
        out[160 + t] = a;
    }
}

extern "C" void kernel_launch(void* const* d_in, const int* in_sizes, int n_in,
                              void* d_out, int out_size, void* d_ws, size_t ws_size,
                              hipStream_t stream) {
    const float* pos   = (const float*)d_in[0];
    const int*   esrc  = (const int*)  d_in[1];
    const float* c1W1 = (const float*)d_in[4];
    const float* c1b1 = (const float*)d_in[5];
    const float* c1W2 = (const float*)d_in[6];
    const float* c1b2 = (const float*)d_in[7];
    const float* c2W1 = (const float*)d_in[8];
    const float* c2b1 = (const float*)d_in[9];
    const float* c2W2 = (const float*)d_in[10];
    const float* c2b2 = (const float*)d_in[11];
    const float* fc1W = (const float*)d_in[12];
    const float* fc1b = (const float*)d_in[13];
    const float* fc2W = (const float*)d_in[14];
    const float* fc2b = (const float*)d_in[15];
    const float* labW = (const float*)d_in[16];
    const float* labb = (const float*)d_in[17];
    const float* boxW = (const float*)d_in[18];
    const float* boxb = (const float*)d_in[19];

    __bf16* wsb = (__bf16*)d_ws;
    __bf16* x1   = wsb + OFF_X1;
    __bf16* p1   = wsb + OFF_P1;
    __bf16* p2   = wsb + OFF_P2;
    __bf16* p3   = wsb + OFF_P3;
    __bf16* p4   = wsb + OFF_P4;
    __bf16* relE = wsb + OFF_RELE;
    unsigned int* pooled = (unsigned int*)((char*)d_ws + OFF_POOL_BYTES);

    pack_weights<<<62, 256, 0, stream>>>(c1W1, c1W2, c2W1, c2W2, p1, p2, p3, p4, pooled, relE);
    conv1_kernel<<<N_NODES / NB1, 256, 0, stream>>>(pos, esrc, p1, c1b1, p2, c1b2, x1, relE);
    conv2_kernel<<<N_NODES / (NB2 * NT2), 512, 0, stream>>>(esrc, x1, relE, p3, c2b1, p4, c2b2, pooled);
    head_kernel<<<1, 256, 0, stream>>>(pooled, fc1W, fc1b, fc2W, fc2b,
                                       labW, labb, boxW, boxb, (float*)d_out);
}

// Round 10
// 237.078 us; speedup vs baseline: 1.2429x; 1.0184x over previous
//
#include <hip/hip_runtime.h>

#define N_NODES 20000
#define DEG 16
#define GRAPHS 16
#define NPG 1250

typedef __bf16 bf16x8 __attribute__((ext_vector_type(8)));
typedef float f32x4 __attribute__((ext_vector_type(4)));
#define MFMA16(a, b, c) __builtin_amdgcn_mfma_f32_16x16x32_bf16(a, b, c, 0, 0, 0)

// async global->LDS direct copy, 16 B per lane; LDS dest = uniform base + lane*16
__device__ __forceinline__ void async16(void* lds, const void* g) {
    __builtin_amdgcn_global_load_lds(
        (const __attribute__((address_space(1))) unsigned int*)(g),
        (__attribute__((address_space(3))) unsigned int*)(lds), 16, 0, 0);
}

// ---- workspace layout (bf16 element offsets) ----
#define OFF_X1    0            // x1 [20000][128] bf16
#define OFF_P1    2560000      // c1W1 packed: MT=8  KT=1 -> 4096
#define OFF_P2    2564096      // c1W2 packed: MT=8  KT=4 -> 16384
#define OFF_P3    2580480      // c2W1 packed: MT=16 KT=5 -> 40960
#define OFF_P4    2621440      // c2W2 packed: MT=16 KT=8 -> 65536
#define OFF_POOL_BYTES 5373952 // pooled u32[16*256]
#define OFF_RELE  2695176      // relE rows of 8 bf16: row (d*16+e) = {rel0,rel1,rel2,0..}
#define RELZ_ROW  320000       //   row 320000 = zeros (written by pack_weights)

__global__ __launch_bounds__(256) void pack_weights(
    const float* __restrict__ c1W1, const float* __restrict__ c1W2,
    const float* __restrict__ c2W1, const float* __restrict__ c2W2,
    __bf16* __restrict__ p1, __bf16* __restrict__ p2,
    __bf16* __restrict__ p3, __bf16* __restrict__ p4,
    unsigned int* __restrict__ pooled, __bf16* __restrict__ relE)
{
    int t = blockIdx.x * 256 + threadIdx.x;
    if (t < GRAPHS * 256) pooled[t] = 0u;             // flipped(-inf) == 0
    if (t == 0) {                                     // zero row for conv2 kt=4 filler lanes
        bf16x8 z;
        #pragma unroll
        for (int j = 0; j < 8; j++) z[j] = (__bf16)0.f;
        *(bf16x8*)&relE[(size_t)RELZ_ROW * 8] = z;
    }
    if (t >= 15872) return;
    const float* W; __bf16* out; int M, Kreal, KT, grp;
    if      (t <  512)  { W = c1W1; out = p1; M = 128; Kreal =   6; KT = 1; grp = t; }
    else if (t < 2560)  { W = c1W2; out = p2; M = 128; Kreal = 128; KT = 4; grp = t - 512; }
    else if (t < 7680)  { W = c2W1; out = p3; M = 256; Kreal = 131; KT = 5; grp = t - 2560; }
    else                { W = c2W2; out = p4; M = 256; Kreal = 256; KT = 8; grp = t - 7680; }
    int lane = grp & 63, rest = grp >> 6;
    int kt = rest % KT, mt = rest / KT;
    int m = mt * 16 + (lane & 15);
    int kbase = kt * 32 + ((lane >> 4) << 3);
    bf16x8 v;
    #pragma unroll
    for (int j = 0; j < 8; j++) {
        int k = kbase + j;
        v[j] = (k < Kreal) ? (__bf16)W[k * M + m] : (__bf16)0.f;
    }
    *(bf16x8*)&out[grp * 8] = v;
}

// =================== conv1 =================== (unchanged from R9)
#define NB1 16
__global__ __launch_bounds__(256, 2) void conv1_kernel(
    const float* __restrict__ pos, const int* __restrict__ esrc,
    const __bf16* __restrict__ W1p, const float* __restrict__ b1,
    const __bf16* __restrict__ W2p, const float* __restrict__ b2,
    __bf16* __restrict__ x1, __bf16* __restrict__ relE)
{
    __shared__ __attribute__((aligned(16))) __bf16 msgF[NB1][16][8];        // 4 KB
    __shared__ __attribute__((aligned(16))) __bf16 hidF[NB1 * 4 * 64 * 8];  // 64 KB
    const int tid = threadIdx.x, lane = tid & 63, wave = tid >> 6;
    const int quad = lane >> 4, col = lane & 15;
    const int node0 = blockIdx.x * NB1;

    bf16x8 A1[2], B2w[2][4];
    f32x4 bias1[2];
    float b2v[2];
    #pragma unroll
    for (int i = 0; i < 2; i++) {
        int mtg = wave * 2 + i;
        A1[i] = *(const bf16x8*)&W1p[(mtg * 64 + lane) * 8];
        bias1[i] = *(const f32x4*)&b1[mtg * 16 + quad * 4];
        #pragma unroll
        for (int kt = 0; kt < 4; kt++)
            B2w[i][kt] = *(const bf16x8*)&W2p[((mtg * 4 + kt) * 64 + lane) * 8];
        b2v[i] = b2[mtg * 16 + col];
    }

    {   // phase 0: fully-parallel gather, one edge per thread
        int nl = tid >> 4, e = tid & 15;
        int d = node0 + nl;
        int s = esrc[d * 16 + e];
        float sx = pos[3*s], sy = pos[3*s+1], sz = pos[3*s+2];
        float dx = pos[3*d], dy = pos[3*d+1], dz = pos[3*d+2];
        __bf16 rx = (__bf16)(sx - dx), ry = (__bf16)(sy - dy), rz = (__bf16)(sz - dz);
        bf16x8 v;
        v[0] = (__bf16)sx; v[1] = (__bf16)sy; v[2] = (__bf16)sz;
        v[3] = rx; v[4] = ry; v[5] = rz;
        v[6] = (__bf16)0.f; v[7] = (__bf16)0.f;
        *(bf16x8*)&msgF[nl][e][0] = v;
        bf16x8 rv;
        rv[0] = rx; rv[1] = ry; rv[2] = rz;
        #pragma unroll
        for (int j = 3; j < 8; j++) rv[j] = (__bf16)0.f;
        *(bf16x8*)&relE[((size_t)d * 16 + e) * 8] = rv;   // conv2 staging source
    }
    __syncthreads();

    // phase 1: layer1 MFMA, write hid frags
    #pragma unroll
    for (int nl = 0; nl < NB1; nl++) {
        bf16x8 B;
        if (quad == 0) {
            B = *(const bf16x8*)&msgF[nl][col][0];
        } else {
            #pragma unroll
            for (int j = 0; j < 8; j++) B[j] = (__bf16)0.f;
        }
        #pragma unroll
        for (int i = 0; i < 2; i++) {
            int mtg = wave * 2 + i;
            f32x4 acc = bias1[i];
            acc = MFMA16(A1[i], B, acc);
            union { __bf16 h[4]; uint2 u; } pk;
            #pragma unroll
            for (int r = 0; r < 4; r++) pk.h[r] = (__bf16)fmaxf(acc[r], 0.f);
            int kt2 = mtg >> 1;
            int lane2 = ((mtg * 2 + (quad >> 1)) & 3) * 16 + col;
            int j0 = (quad & 1) * 4;
            *(uint2*)&hidF[((nl * 4 + kt2) * 64 + lane2) * 8 + j0] = pk.u;
        }
    }
    __syncthreads();

    // phase 2: D[edge][ch], edge-max, write x1
    #pragma unroll
    for (int nl = 0; nl < NB1; nl++) {
        bf16x8 hA[4];
        #pragma unroll
        for (int kt = 0; kt < 4; kt++)
            hA[kt] = *(const bf16x8*)&hidF[((nl * 4 + kt) * 64 + lane) * 8];
        f32x4 acc[2];
        f32x4 z = {0.f, 0.f, 0.f, 0.f};
        acc[0] = z; acc[1] = z;
        #pragma unroll
        for (int kt = 0; kt < 4; kt++) {
            #pragma unroll
            for (int i = 0; i < 2; i++) acc[i] = MFMA16(hA[kt], B2w[i][kt], acc[i]);
        }
        #pragma unroll
        for (int i = 0; i < 2; i++) {
            int mtg = wave * 2 + i;
            float m = fmaxf(fmaxf(acc[i][0], acc[i][1]), fmaxf(acc[i][2], acc[i][3]));
            m = fmaxf(m, __shfl_xor(m, 16));
            m = fmaxf(m, __shfl_xor(m, 32));
            if (lane < 16)
                x1[(size_t)(node0 + nl) * 128 + mtg * 16 + lane] = (__bf16)(m + b2v[i]);
        }
    }
}

// =================== conv2 ===================
// 500 blocks x 512 threads x 40 nodes (NT2=20 tiles of NB2=2), SPECIALIZED:
// waves 0-3 = layer1 producers (A1[4][5]+bias resident, read msgF only),
// waves 4-7 = layer2 consumers (B2r[4][8] resident, read hidF only).
// Halves per-tile LDS read volume vs unified (4 waves x full msgF + 4 x full
// hidF instead of 8 x both) and halves each wave's per-tile dependency chain.
// msgF staged PURE ASYNC (global_load_lds 16B); edge indices for tile k+2
// prefetched into producer registers during tile k (no sSrc, no LDS dep).
#define NB2 2
#define NT2 20
__global__ __launch_bounds__(512) __attribute__((amdgpu_waves_per_eu(2, 2)))
void conv2_kernel(
    const int* __restrict__ esrc,
    const __bf16* __restrict__ x1, const __bf16* __restrict__ relE,
    const __bf16* __restrict__ W1p, const float* __restrict__ b1,
    const __bf16* __restrict__ W2p, const float* __restrict__ b2,
    unsigned int* __restrict__ pooled)
{
    __shared__ __attribute__((aligned(16))) __bf16 msgF[2][NB2 * 5 * 64 * 8];  // 2x10 KB
    __shared__ __attribute__((aligned(16))) __bf16 hidF[2][NB2 * 8 * 64 * 8];  // 2x16 KB
    const int tid = threadIdx.x, lane = tid & 63, wave = tid >> 6;
    const int quad = lane >> 4, col = lane & 15;
    const int base = blockIdx.x * (NB2 * NT2);

    if (wave < 4) {
        // ===== producer: layer 1 =====
        bf16x8 A1[4][5];
        f32x4 bias1[4];
        #pragma unroll
        for (int i = 0; i < 4; i++) {
            int tg = wave * 4 + i;
            #pragma unroll
            for (int kt = 0; kt < 5; kt++)
                A1[i][kt] = *(const bf16x8*)&W1p[((tg * 5 + kt) * 64 + lane) * 8];
            bias1[i] = *(const f32x4*)&b1[tg * 16 + quad * 4];
        }

        int srcN[2];   // edge-src for the NEXT tile to stage (per nl), prefetched
        auto loadsrc = [&](int tk) {
            if (tk < NT2) {
                int d0 = base + tk * NB2;
                srcN[0] = esrc[d0 * 16 + col];
                srcN[1] = esrc[(d0 + 1) * 16 + col];
            }
        };
        // stage tile tk into msgF[tk&1] using srcN (loaded for tile tk)
        auto stage = [&](int tk) {
            int buf = tk & 1;
            #pragma unroll
            for (int s = 0; s < 3; s++) {
                int g = wave + 4 * s;
                if (g < 10) {
                    int nl = g / 5, kt = g % 5;
                    __bf16* ldst = &msgF[buf][g * 64 * 8];   // + lane*16 implicit
                    const __bf16* gsrc;
                    if (kt < 4) {
                        gsrc = &x1[(size_t)srcN[nl] * 128 + kt * 32 + quad * 8];
                    } else {
                        int row = (quad == 0) ? ((base + tk * NB2 + nl) * 16 + col) : RELZ_ROW;
                        gsrc = &relE[(size_t)row * 8];
                    }
                    async16(ldst, gsrc);
                }
            }
        };

        loadsrc(0);
        stage(0);
        loadsrc(1);
        __syncthreads();                 // drain tile-0 DMA

        for (int k = 0; k < NT2; k++) {
            const int buf = k & 1;
            if (k + 1 < NT2) stage(k + 1);   // uses srcN for tile k+1
            loadsrc(k + 2);                  // prefetch indices for tile k+2
            // layer1 tile k: msgF[buf] -> hidF[buf]
            #pragma unroll
            for (int nl = 0; nl < NB2; nl++) {
                bf16x8 B[5];
                #pragma unroll
                for (int kt = 0; kt < 5; kt++)
                    B[kt] = *(const bf16x8*)&msgF[buf][((nl * 5 + kt) * 64 + lane) * 8];
                #pragma unroll
                for (int i = 0; i < 4; i++) {
                    int mtg = wave * 4 + i;
                    f32x4 acc = bias1[i];
                    #pragma unroll
                    for (int kt = 0; kt < 5; kt++) acc = MFMA16(A1[i][kt], B[kt], acc);
                    union { __bf16 h[4]; uint2 u; } pk;
                    #pragma unroll
                    for (int r = 0; r < 4; r++) pk.h[r] = (__bf16)fmaxf(acc[r], 0.f);
                    int kt2 = mtg >> 1;
                    int lane2 = ((mtg * 2 + (quad >> 1)) & 3) * 16 + col;
                    int j0 = (quad & 1) * 4;
                    *(uint2*)&hidF[buf][((nl * 8 + kt2) * 64 + lane2) * 8 + j0] = pk.u;
                }
            }
            __syncthreads();
        }
    } else {
        // ===== consumer: layer 2 + fused global max-pool =====
        const int wv = wave - 4;
        bf16x8 B2r[4][8];
        #pragma unroll
        for (int i = 0; i < 4; i++) {
            int tg = wv * 4 + i;
            #pragma unroll
            for (int kt = 0; kt < 8; kt++)
                B2r[i][kt] = *(const bf16x8*)&W2p[((tg * 8 + kt) * 64 + lane) * 8];
        }
        f32x4 runmax[4];
        #pragma unroll
        for (int i = 0; i < 4; i++)
            #pragma unroll
            for (int r = 0; r < 4; r++) runmax[i][r] = -3.4e38f;
        int gprev = base / NPG;

        auto flushfn = [&]() {
            #pragma unroll
            for (int i = 0; i < 4; i++) {
                float v = fmaxf(fmaxf(runmax[i][0], runmax[i][1]),
                                fmaxf(runmax[i][2], runmax[i][3]));
                v = fmaxf(v, __shfl_xor(v, 16));
                v = fmaxf(v, __shfl_xor(v, 32));
                if (lane < 16) {
                    int c = (wv * 4 + i) * 16 + lane;
                    float val = v + b2[c];
                    unsigned u = __float_as_uint(val);
                    u = (u & 0x80000000u) ? ~u : (u | 0x80000000u);
                    atomicMax(&pooled[gprev * 256 + c], u);
                }
                #pragma unroll
                for (int r = 0; r < 4; r++) runmax[i][r] = -3.4e38f;
            }
        };
        auto consume = [&](int tk) {     // layer2 for tile tk from hidF[tk&1]
            int buf1 = tk & 1;
            int n0 = base + tk * NB2;
            #pragma unroll
            for (int nl = 0; nl < NB2; nl++) {
                int g = (n0 + nl) / NPG;
                if (g != gprev) { flushfn(); gprev = g; }
                bf16x8 hA[8];
                #pragma unroll
                for (int kt = 0; kt < 8; kt++)
                    hA[kt] = *(const bf16x8*)&hidF[buf1][((nl * 8 + kt) * 64 + lane) * 8];
                f32x4 acc[4];
                f32x4 z = {0.f, 0.f, 0.f, 0.f};
                #pragma unroll
                for (int i = 0; i < 4; i++) acc[i] = z;
                #pragma unroll
                for (int kt = 0; kt < 8; kt++) {
                    #pragma unroll
                    for (int i = 0; i < 4; i++) acc[i] = MFMA16(hA[kt], B2r[i][kt], acc[i]);
                }
                #pragma unroll
                for (int i = 0; i < 4; i++)
                    #pragma unroll
                    for (int r = 0; r < 4; r++)
                        runmax[i][r] = fmaxf(runmax[i][r], acc[i][r]);
            }
        };

        __syncthreads();                 // match producer's post-stage-0 barrier
        for (int k = 0; k < NT2; k++) {
            if (k > 0) consume(k - 1);
            __syncthreads();
        }
        consume(NT2 - 1);
        flushfn();
    }
}

// =================== head (tiny, fp32) ===================
__global__ __launch_bounds__(256) void head_kernel(
    const unsigned int* __restrict__ pooled,
    const float* __restrict__ fc1_W, const float* __restrict__ fc1_b,
    const float* __restrict__ fc2_W, const float* __restrict__ fc2_b,
    const float* __restrict__ lab_W, const float* __restrict__ lab_b,
    const float* __restrict__ box_W, const float* __restrict__ box_b,
    float* __restrict__ out)
{
    __shared__ float p [GRAPHS][256];
    __shared__ float h1[GRAPHS][256];
    __shared__ float h2[GRAPHS][128];
    const int c = threadIdx.x;

    #pragma unroll
    for (int g = 0; g < GRAPHS; g++) {
        unsigned u = pooled[g*256 + c];
        u = (u & 0x80000000u) ? (u & 0x7fffffffu) : ~u;
        p[g][c] = __uint_as_float(u);
    }
    __syncthreads();

    float acc[GRAPHS];
    float bb = fc1_b[c];
    #pragma unroll
    for (int g = 0; g < GRAPHS; g++) acc[g] = bb;
    for (int k = 0; k < 256; k++) {
        float w = fc1_W[k*256 + c];
        #pragma unroll
        for (int g = 0; g < GRAPHS; g++) acc[g] += p[g][k] * w;
    }
    #pragma unroll
    for (int g = 0; g < GRAPHS; g++) h1[g][c] = fmaxf(acc[g], 0.0f);
    __syncthreads();

    if (c < 128) {
        float bb2 = fc2_b[c];
        #pragma unroll
        for (int g = 0; g < GRAPHS; g++) acc[g] = bb2;
        for (int k = 0; k < 256; k++) {
            float w = fc2_W[k*128 + c];
            #pragma unroll
            for (int g = 0; g < GRAPHS; g++) acc[g] += h1[g][k] * w;
        }
        #pragma unroll
        for (int g = 0; g < GRAPHS; g++) h2[g][c] = fmaxf(acc[g], 0.0f);
    }
    __syncthreads();

    if (c < 160) {
        int g = c / 10, j = c % 10;
        float a = lab_b[j];
        for (int k = 0; k < 128; k++) a += h2[g][k] * lab_W[k*10 + j];
        out[c] = a;
    } else {
        int t = c - 160;
        int g = t / 6, j = t % 6;
        float a = box_b[j];
        for (int k = 0; k < 128; k++) a += h2[g][k] * box_W[k*6 + j];
        out[160 + t] = a;
    }
}

extern "C" void kernel_launch(void* const* d_in, const int* in_sizes, int n_in,
                              void* d_out, int out_size, void* d_ws, size_t ws_size,
                              hipStream_t stream) {
    const float* pos   = (const float*)d_in[0];
    const int*   esrc  = (const int*)  d_in[1];
    const float* c1W1 = (const float*)d_in[4];
    const float* c1b1 = (const float*)d_in[5];
    const float* c1W2 = (const float*)d_in[6];
    const float* c1b2 = (const float*)d_in[7];
    const float* c2W1 = (const float*)d_in[8];
    const float* c2b1 = (const float*)d_in[9];
    const float* c2W2 = (const float*)d_in[10];
    const float* c2b2 = (const float*)d_in[11];
    const float* fc1W = (const float*)d_in[12];
    const float* fc1b = (const float*)d_in[13];
    const float* fc2W = (const float*)d_in[14];
    const float* fc2b = (const float*)d_in[15];
    const float* labW = (const float*)d_in[16];
    const float* labb = (const float*)d_in[17];
    const float* boxW = (const float*)d_in[18];
    const float* boxb = (const float*)d_in[19];

    __bf16* wsb = (__bf16*)d_ws;
    __bf16* x1   = wsb + OFF_X1;
    __bf16* p1   = wsb + OFF_P1;
    __bf16* p2   = wsb + OFF_P2;
    __bf16* p3   = wsb + OFF_P3;
    __bf16* p4   = wsb + OFF_P4;
    __bf16* relE = wsb + OFF_RELE;
    unsigned int* pooled = (unsigned int*)((char*)d_ws + OFF_POOL_BYTES);

    pack_weights<<<62, 256, 0, stream>>>(c1W1, c1W2, c2W1, c2W2, p1, p2, p3, p4, pooled, relE);
    conv1_kernel<<<N_NODES / NB1, 256, 0, stream>>>(pos, esrc, p1, c1b1, p2, c1b2, x1, relE);
    conv2_kernel<<<N_NODES / (NB2 * NT2), 512, 0, stream>>>(esrc, x1, relE, p3, c2b1, p4, c2b2, pooled);
    head_kernel<<<1, 256, 0, stream>>>(pooled, fc1W, fc1b, fc2W, fc2b,
                                       labW, labb, boxW, boxb, (float*)d_out);
}